// Round 10
// baseline (293.629 us; speedup 1.0000x reference)
//
#include <hip/hip_runtime.h>
#include <hip/hip_bf16.h>

#define B 2
#define S 8192
#define H 16
#define D 64
#define NB 32          // S / BS
#define BS 256
#define SAMP 256
#define BH (B*H)
#define BHS (B*H*S)
#define BSHD (B*S*H*D)
#define LOG32 3.4657359027997265f   // log(8192/256)

typedef float f32x4 __attribute__((ext_vector_type(4)));
typedef short bf16x8 __attribute__((ext_vector_type(8)));

__device__ __forceinline__ unsigned short f2bf(float x) {
    unsigned int u = __builtin_bit_cast(unsigned int, x);
    u += 0x7fffu + ((u >> 16) & 1u);       // round-to-nearest-even
    return (unsigned short)(u >> 16);
}
__device__ __forceinline__ unsigned int pack2(float a, float b) {
    return (unsigned int)f2bf(a) | ((unsigned int)f2bf(b) << 16);
}

// ---------------------------------------------------------------------------
// Kernel 1: LSH hash (Q and K) + bf16 pack of K.  Blocks [0,2048) hash Q;
// [2048,4096) hash+pack K.  Quad-cooperative, 2 ROWS per quad (was 4):
// halves per-thread dependency chains, ~50 live VGPR -> launch_bounds(256,6)
// gives 24 waves/CU (was 16).  Per-instruction footprint stays 16 x 64B
// fully-consumed chunks.  spd replicated 4x at pitch 520 (conflict-free);
// kbf stores pair-merged via shfl_xor(1).  V is staged by attn from f32.
// ---------------------------------------------------------------------------
__global__ __launch_bounds__(256, 6) void k_hash(const float* __restrict__ q,
                                                 const float* __restrict__ k,
                                                 const float* __restrict__ pd,
                                                 int* __restrict__ hq,
                                                 int* __restrict__ hk,
                                                 unsigned short* __restrict__ kbf) {
    __shared__ float spd4[4 * 520];
    const int t = threadIdx.x;
    for (int i = t; i < 512; i += 256) {
        const float val = pd[i];
        spd4[i] = val; spd4[520 + i] = val;
        spd4[1040 + i] = val; spd4[1560 + i] = val;
    }
    __syncthreads();

    const bool isK = blockIdx.x >= 2048;
    const int  blk = blockIdx.x & 2047;
    const float* src = isK ? k : q;
    int* hdst = isK ? hk : hq;

    const int lane = t & 63;
    const int c    = lane & 3;                         // dim-quarter owner
    const int rowq = blk * 128 + (t >> 6) * 32 + (lane >> 2) * 2;
    const int myrow = rowq + (c & 1);                  // row lanes c<2 emit
    const int mb = myrow >> 17, ms = (myrow >> 4) & (S - 1), mh = myrow & (H - 1);
    const int hout = (mb * H + mh) * S + ms;
    const float* sp = spd4 + c * 520;

    float d[2][8];
#pragma unroll
    for (int rr = 0; rr < 2; ++rr)
#pragma unroll
        for (int p = 0; p < 8; ++p) d[rr][p] = 0.f;

#pragma unroll
    for (int j = 0; j < 4; ++j) {
        float4 x[2];
#pragma unroll
        for (int rr = 0; rr < 2; ++rr)
            x[rr] = *(const float4*)(src + ((rowq + rr) << 6) + j * 16 + c * 4);

        if (isK) {
#pragma unroll
            for (int rr = 0; rr < 2; ++rr) {
                uint2 u2;
                u2.x = pack2(x[rr].x, x[rr].y);
                u2.y = pack2(x[rr].z, x[rr].w);
                uint2 po;
                po.x = __shfl_xor(u2.x, 1);
                po.y = __shfl_xor(u2.y, 1);
                if (!(c & 1)) {
                    uint4 o; o.x = u2.x; o.y = u2.y; o.z = po.x; o.w = po.y;
                    *(uint4*)(kbf + ((rowq + rr) << 6) + j * 16 + c * 4) = o;
                }
            }
        }
#pragma unroll
        for (int u = 0; u < 4; ++u) {
            const int dim = j * 16 + c * 4 + u;
            float4 s0 = *(const float4*)&sp[dim * 8];
            float4 s1 = *(const float4*)&sp[dim * 8 + 4];
#pragma unroll
            for (int rr = 0; rr < 2; ++rr) {
                const float xv = (u == 0) ? x[rr].x : (u == 1) ? x[rr].y
                               : (u == 2) ? x[rr].z : x[rr].w;
                d[rr][0] += xv * s0.x; d[rr][1] += xv * s0.y;
                d[rr][2] += xv * s0.z; d[rr][3] += xv * s0.w;
                d[rr][4] += xv * s1.x; d[rr][5] += xv * s1.y;
                d[rr][6] += xv * s1.z; d[rr][7] += xv * s1.w;
            }
        }
    }
#pragma unroll
    for (int rr = 0; rr < 2; ++rr)
#pragma unroll
        for (int p = 0; p < 8; ++p) {
            d[rr][p] += __shfl_xor(d[rr][p], 1);
            d[rr][p] += __shfl_xor(d[rr][p], 2);
        }
    int bits[2];
#pragma unroll
    for (int rr = 0; rr < 2; ++rr) {
        int bv = 0;
#pragma unroll
        for (int p = 0; p < 8; ++p) bv |= (d[rr][p] > 0.f) ? (1 << p) : 0;
        bits[rr] = bv;
    }
    if (c < 2) {
        const int myb = (c & 1) ? bits[1] : bits[0];
        hdst[hout] = myb ^ (myb >> 1);
    }
}

// ---------------------------------------------------------------------------
// Kernel 2: stable counting sort (argsort) of hashes per (b,h).  (unchanged)
// ---------------------------------------------------------------------------
#define SORT_NT 64
#define SORT_CH (S / SORT_NT)   // 128

__global__ __launch_bounds__(SORT_NT) void k_sort(const int* __restrict__ hq,
                                                  const int* __restrict__ hk,
                                                  int* __restrict__ qs,
                                                  int* __restrict__ ks) {
    __shared__ int hist[SORT_NT * 256];
    __shared__ int base[257];
    const int t  = threadIdx.x;
    const int bh = blockIdx.x & (BH - 1);
    const bool isQ = blockIdx.x < BH;
    const int* hp = (isQ ? hq : hk) + bh * S;
    int*       sp = (isQ ? qs : ks) + bh * S;

    for (int i = 0; i < 256; ++i) hist[t * 256 + i] = 0;
    __syncthreads();
    for (int i = 0; i < SORT_CH; ++i) hist[t * 256 + hp[t * SORT_CH + i]]++;
    __syncthreads();

    for (int bi = 0; bi < 4; ++bi) {
        const int bin = t * 4 + bi;
        int sum = 0;
        for (int tt = 0; tt < SORT_NT; ++tt) sum += hist[tt * 256 + bin];
        base[bin + 1] = sum;
    }
    __syncthreads();
    if (t == 0) {
        base[0] = 0;
        for (int i = 1; i <= 256; ++i) base[i] += base[i - 1];
    }
    __syncthreads();

    for (int bi = 0; bi < 4; ++bi) {
        const int bin = t * 4 + bi;
        int run = base[bin];
        for (int tt = 0; tt < SORT_NT; ++tt) {
            int c = hist[tt * 256 + bin];
            hist[tt * 256 + bin] = run;
            run += c;
        }
    }
    __syncthreads();

    for (int i = 0; i < SORT_CH; ++i) {
        const int s0  = t * SORT_CH + i;
        const int bin = hp[s0];
        sp[hist[t * 256 + bin]++] = s0;
    }
}

// ---------------------------------------------------------------------------
// Kernel 3: FUSED attention.  (512,2): VGPR budget 128 = the 2-blocks/CU
// boundary (4 waves/SIMD x 128 = 512).  All 8 K-gathers of a kt4 issued
// BEFORE the MFMA groups (kf=1 latency hides under kf=0 compute); key
// indices krw[4] computed per-kt4 (not hoisted) to stay under 128 VGPR.
// V staged from f32 with issue-early loads, packed to bf16 pre-barrier.
// ---------------------------------------------------------------------------
#define VP 264    // vT pitch (256 + 8 pad)
#define PP 40     // per-wave P pitch (32 + 8 pad)

__global__ __launch_bounds__(512, 2) void k_attn(const float* __restrict__ q,
                                                 const unsigned short* __restrict__ kbf,
                                                 const float* __restrict__ v,
                                                 const int* __restrict__ qs,
                                                 const int* __restrict__ ks,
                                                 const int* __restrict__ sidx,
                                                 float* __restrict__ out) {
    __shared__ __align__(16) unsigned short vT[64 * VP];
    __shared__ __align__(16) unsigned short pL[8 * 32 * PP];

    const int t    = threadIdx.x;
    const int w    = t >> 6;
    const int lane = t & 63;
    const int lg   = lane >> 4;      // 0..3
    const int lr   = lane & 15;      // 0..15
    // XCD swizzle: all 32 blocks of one (b,h) land on one XCD
    const int logical = (blockIdx.x & 7) * (BH * NB / 8) + (blockIdx.x >> 3);
    const int blk  = logical & (NB - 1);
    const int bh   = logical >> 5;
    const int h    = bh & (H - 1), b = bh >> 4;
    const int sbase = bh * S + blk * BS;
    unsigned short* pw = pL + w * 32 * PP;

    // ---- Q B-fragments from f32 (scale 1/8 folded into cvt) ----
    int qrow[2]; bf16x8 bq[2][2];
#pragma unroll
    for (int qg = 0; qg < 2; ++qg) {
        qrow[qg] = qs[sbase + w * 32 + qg * 16 + lr];
        const float* qp = q + (((b * S + qrow[qg]) * H + h) << 6);
#pragma unroll
        for (int kf = 0; kf < 2; ++kf) {
            float4 x0 = ((const float4*)(qp + kf * 32 + lg * 8))[0];
            float4 x1 = ((const float4*)(qp + kf * 32 + lg * 8))[1];
            union { bf16x8 v8; unsigned int u[4]; } fa;
            fa.u[0] = pack2(x0.x * 0.125f, x0.y * 0.125f);
            fa.u[1] = pack2(x0.z * 0.125f, x0.w * 0.125f);
            fa.u[2] = pack2(x1.x * 0.125f, x1.y * 0.125f);
            fa.u[3] = pack2(x1.z * 0.125f, x1.w * 0.125f);
            bq[qg][kf] = fa.v8;
        }
    }

    float m_run[2] = {-1e30f, -1e30f}, l_run[2] = {0.f, 0.f};
    f32x4 acc[2][4];
#pragma unroll
    for (int qg = 0; qg < 2; ++qg)
#pragma unroll
        for (int dg = 0; dg < 4; ++dg) acc[qg][dg] = (f32x4){0.f, 0.f, 0.f, 0.f};

    for (int pass = 0; pass < 2; ++pass) {
        {   // ---- stage V^T from f32: load+convert EARLY, write after barrier ----
            const int key = t >> 1, d0 = (t & 1) * 32;
            const int krow = pass ? sidx[bh * SAMP + key] : ks[sbase + key];
            const float* vp = v + (((b * S + krow) * H + h) << 6) + d0;
            unsigned int uv[16];
#pragma unroll
            for (int i = 0; i < 8; ++i) {
                float4 y = ((const float4*)vp)[i];
                uv[2 * i]     = pack2(y.x, y.y);
                uv[2 * i + 1] = pack2(y.z, y.w);
            }
            if (pass) __syncthreads();          // all reads of old vT done
#pragma unroll
            for (int j = 0; j < 16; ++j) {
                const int d = d0 + 2 * j;
                vT[(d + 0) * VP + key] = (unsigned short)(uv[j]);
                vT[(d + 1) * VP + key] = (unsigned short)(uv[j] >> 16);
            }
        }
        __syncthreads();

        const float bias = pass ? LOG32 : 0.f;
#pragma unroll
        for (int kt4 = 0; kt4 < 4; ++kt4) {
            // ---- key rows for this tile + ALL 8 K-gathers issued upfront ----
            int krw[4];
#pragma unroll
            for (int kg = 0; kg < 4; ++kg) {
                const int key = kt4 * 64 + kg * 16 + lr;
                krw[kg] = pass ? sidx[bh * SAMP + key] : ks[sbase + key];
            }
            bf16x8 ak[2][4];
#pragma unroll
            for (int kg = 0; kg < 4; ++kg) {
                const unsigned short* kp = kbf + (((b * S + krw[kg]) * H + h) << 6) + lg * 8;
                ak[0][kg] = *(const bf16x8*)(kp);
                ak[1][kg] = *(const bf16x8*)(kp + 32);
            }
            // ---- S^T = K Q^T  (A=K frags, B=Q frags) ----
            f32x4 c[2][4];
            __builtin_amdgcn_s_setprio(1);
#pragma unroll
            for (int kf = 0; kf < 2; ++kf)
#pragma unroll
                for (int qg = 0; qg < 2; ++qg)
#pragma unroll
                    for (int kg = 0; kg < 4; ++kg) {
                        f32x4 cin = kf ? c[qg][kg] : (f32x4){0.f, 0.f, 0.f, 0.f};
                        c[qg][kg] = __builtin_amdgcn_mfma_f32_16x16x32_bf16(ak[kf][kg], bq[qg][kf], cin, 0, 0, 0);
                    }
            __builtin_amdgcn_s_setprio(0);
            // ---- online softmax with defer-max (keys in-lane) ----
#pragma unroll
            for (int qg = 0; qg < 2; ++qg) {
                float tm = -1e30f;
#pragma unroll
                for (int kg = 0; kg < 4; ++kg)
#pragma unroll
                    for (int r = 0; r < 4; ++r) tm = fmaxf(tm, c[qg][kg][r]);
                tm = fmaxf(tm, __shfl_xor(tm, 16));
                tm = fmaxf(tm, __shfl_xor(tm, 32));
                tm += bias;
                if (!__all(tm <= m_run[qg] + 8.f)) {
                    const float mn  = fmaxf(m_run[qg], tm);
                    const float es  = __expf(m_run[qg] - mn);
                    m_run[qg] = mn;
                    l_run[qg] *= es;
#pragma unroll
                    for (int r = 0; r < 4; ++r) {
                        const float er = __shfl(es, lg * 4 + r);
#pragma unroll
                        for (int dg = 0; dg < 4; ++dg) acc[qg][dg][r] *= er;
                    }
                }
                const float mnb = m_run[qg] - bias;
                float rs = 0.f;
#pragma unroll
                for (int kg = 0; kg < 4; ++kg)
#pragma unroll
                    for (int r = 0; r < 4; ++r) {
                        const float p = __expf(c[qg][kg][r] - mnb);
                        c[qg][kg][r] = p;
                        rs += p;
                    }
                rs += __shfl_xor(rs, 16);
                rs += __shfl_xor(rs, 32);
                l_run[qg] += rs;
            }
            // ---- PV in 32-key halves: packed P write, b128 reads ----
#pragma unroll
            for (int hh = 0; hh < 2; ++hh) {
#pragma unroll
                for (int qg = 0; qg < 2; ++qg)
#pragma unroll
                    for (int kg2 = 0; kg2 < 2; ++kg2) {
                        const int kg = hh * 2 + kg2;
                        uint2 u;
                        u.x = pack2(c[qg][kg][0], c[qg][kg][1]);
                        u.y = pack2(c[qg][kg][2], c[qg][kg][3]);
                        *(uint2*)&pw[(qg * 16 + lr) * PP + kg2 * 16 + lg * 4] = u;
                    }
                bf16x8 bv[4];
#pragma unroll
                for (int dg = 0; dg < 4; ++dg)
                    bv[dg] = *(const bf16x8*)&vT[(dg * 16 + lr) * VP + kt4 * 64 + hh * 32 + lg * 8];
                bf16x8 ap[2];
#pragma unroll
                for (int qg = 0; qg < 2; ++qg)
                    ap[qg] = *(const bf16x8*)&pw[(qg * 16 + lr) * PP + lg * 8];
                __builtin_amdgcn_s_setprio(1);
#pragma unroll
                for (int qg = 0; qg < 2; ++qg)
#pragma unroll
                    for (int dg = 0; dg < 4; ++dg)
                        acc[qg][dg] = __builtin_amdgcn_mfma_f32_16x16x32_bf16(ap[qg], bv[dg], acc[qg][dg], 0, 0, 0);
                __builtin_amdgcn_s_setprio(0);
            }
        }
    }

    // ---- epilogue: out = acc / l, scattered to original query order ----
#pragma unroll
    for (int qg = 0; qg < 2; ++qg)
#pragma unroll
        for (int r = 0; r < 4; ++r) {
            const float lq = __shfl(l_run[qg], lg * 4 + r);
            const int   qr = __shfl(qrow[qg], lg * 4 + r);
            const float inv = 1.f / lq;
            const int obase = ((b * S + qr) * H + h) << 6;
#pragma unroll
            for (int dg = 0; dg < 4; ++dg)
                out[obase + dg * 16 + lr] = acc[qg][dg][r] * inv;
        }
}

// ---------------------------------------------------------------------------
extern "C" void kernel_launch(void* const* d_in, const int* in_sizes, int n_in,
                              void* d_out, int out_size, void* d_ws, size_t ws_size,
                              hipStream_t stream) {
    const float* q   = (const float*)d_in[0];
    const float* k   = (const float*)d_in[1];
    const float* v   = (const float*)d_in[2];
    const float* pd  = (const float*)d_in[3];
    const int*  sidx = (const int*)d_in[4];
    float* out = (float*)d_out;

    int* hq = (int*)d_ws;
    int* hk = hq + BHS;
    int* qs = hk + BHS;
    int* ks = qs + BHS;
    unsigned short* kbf = (unsigned short*)(ks + BHS);

    k_hash<<<4096, 256, 0, stream>>>(q, k, pd, hq, hk, kbf);
    k_sort<<<2 * BH, SORT_NT, 0, stream>>>(hq, hk, qs, ks);
    k_attn<<<BH * NB, 512, 0, stream>>>(q, kbf, v, qs, ks, sidx, out);
}

// Round 11
// 195.555 us; speedup vs baseline: 1.5015x; 1.5015x over previous
//
#include <hip/hip_runtime.h>
#include <hip/hip_bf16.h>

#define B 2
#define S 8192
#define H 16
#define D 64
#define NB 32          // S / BS
#define BS 256
#define SAMP 256
#define BH (B*H)
#define BHS (B*H*S)
#define BSHD (B*S*H*D)
#define LOG32 3.4657359027997265f   // log(8192/256)

typedef float f32x4 __attribute__((ext_vector_type(4)));
typedef short bf16x8 __attribute__((ext_vector_type(8)));

__device__ __forceinline__ unsigned short f2bf(float x) {
    unsigned int u = __builtin_bit_cast(unsigned int, x);
    u += 0x7fffu + ((u >> 16) & 1u);       // round-to-nearest-even
    return (unsigned short)(u >> 16);
}
__device__ __forceinline__ unsigned int pack2(float a, float b) {
    return (unsigned int)f2bf(a) | ((unsigned int)f2bf(b) << 16);
}

// ---------------------------------------------------------------------------
// Kernel 1: LSH hash (Q and K) + bf16 pack of K.  Blocks [0,1024) hash Q;
// [1024,2048) hash+pack K.  R9's quad-cooperative compute (4 rows/quad,
// 16x64B fully-consumed read chunks; spd x4 at pitch 520, conflict-free).
// NEW: stores go through LDS.  Packed K rows land in tile[256][34 dwords]
// (pitch 34: b64-aligned, quad-spread banks), then the store phase writes
// kbf as 8 x (256 thr x 16B) = 4KB fully-contiguous per instruction -- the
// R10 lesson: partial-sector stores amplified HBM writes 5.3x (378 MB vs
// 71 MB payload).  Hashes stage via ht[16][16] -> coalesced int4 stores.
// ---------------------------------------------------------------------------
#define HP 34   // tile pitch in dwords (136 B / row)

__global__ __launch_bounds__(256, 3) void k_hash(const float* __restrict__ q,
                                                 const float* __restrict__ k,
                                                 const float* __restrict__ pd,
                                                 int* __restrict__ hq,
                                                 int* __restrict__ hk,
                                                 unsigned short* __restrict__ kbf) {
    __shared__ float spd4[4 * 520];          // 8320 B
    __shared__ unsigned int tile[256 * HP];  // 34816 B
    __shared__ int ht[16][16];               // 1024 B
    const int t = threadIdx.x;
    for (int i = t; i < 512; i += 256) {
        const float val = pd[i];
        spd4[i] = val; spd4[520 + i] = val;
        spd4[1040 + i] = val; spd4[1560 + i] = val;
    }
    __syncthreads();

    const bool isK = blockIdx.x >= 1024;
    const int  blk = blockIdx.x & 1023;
    const float* src = isK ? k : q;
    int* hdst = isK ? hk : hq;

    const int lane = t & 63;
    const int c    = lane & 3;                          // dim-quarter owner
    const int rql  = (t >> 6) * 64 + (lane >> 2) * 4;   // local row base of quad
    const int rowq = blk * 256 + rql;
    const float* sp = spd4 + c * 520;

    float d[4][8];
#pragma unroll
    for (int rr = 0; rr < 4; ++rr)
#pragma unroll
        for (int p = 0; p < 8; ++p) d[rr][p] = 0.f;

#pragma unroll
    for (int j = 0; j < 4; ++j) {
        float4 x[4];
#pragma unroll
        for (int rr = 0; rr < 4; ++rr)
            x[rr] = *(const float4*)(src + ((rowq + rr) << 6) + j * 16 + c * 4);

        if (isK) {
#pragma unroll
            for (int rr = 0; rr < 4; ++rr) {
                uint2 u2;
                u2.x = pack2(x[rr].x, x[rr].y);
                u2.y = pack2(x[rr].z, x[rr].w);
                *(uint2*)&tile[(rql + rr) * HP + j * 8 + c * 2] = u2;
            }
        }
#pragma unroll
        for (int u = 0; u < 4; ++u) {
            const int dim = j * 16 + c * 4 + u;
            float4 s0 = *(const float4*)&sp[dim * 8];
            float4 s1 = *(const float4*)&sp[dim * 8 + 4];
#pragma unroll
            for (int rr = 0; rr < 4; ++rr) {
                const float xv = (u == 0) ? x[rr].x : (u == 1) ? x[rr].y
                               : (u == 2) ? x[rr].z : x[rr].w;
                d[rr][0] += xv * s0.x; d[rr][1] += xv * s0.y;
                d[rr][2] += xv * s0.z; d[rr][3] += xv * s0.w;
                d[rr][4] += xv * s1.x; d[rr][5] += xv * s1.y;
                d[rr][6] += xv * s1.z; d[rr][7] += xv * s1.w;
            }
        }
    }
#pragma unroll
    for (int rr = 0; rr < 4; ++rr)
#pragma unroll
        for (int p = 0; p < 8; ++p) {
            d[rr][p] += __shfl_xor(d[rr][p], 1);
            d[rr][p] += __shfl_xor(d[rr][p], 2);
        }
    int bits[4];
#pragma unroll
    for (int rr = 0; rr < 4; ++rr) {
        int bv = 0;
#pragma unroll
        for (int p = 0; p < 8; ++p) bv |= (d[rr][p] > 0.f) ? (1 << p) : 0;
        bits[rr] = bv;
    }
    const int myb = (c == 0) ? bits[0] : (c == 1) ? bits[1]
                  : (c == 2) ? bits[2] : bits[3];
    const int myrl = rql + c;                 // local row this lane emits
    ht[myrl & 15][myrl >> 4] = myb ^ (myb >> 1);
    __syncthreads();

    // ---- store phase ----
    if (isK) {
        uint4* dst = (uint4*)(kbf + blk * 256 * 64);   // block-contiguous 32KB
#pragma unroll
        for (int it = 0; it < 8; ++it) {
            const int g = it * 256 + t;                // 256 x 16B = 4KB / instr
            const unsigned int* sl = &tile[(g >> 3) * HP + (g & 7) * 4];
            uint4 val;
            val.x = sl[0]; val.y = sl[1]; val.z = sl[2]; val.w = sl[3];
            dst[g] = val;
        }
    }
    if (t < 64) {       // 16 h-planes x 4 int4 = 64 coalesced stores
        const int h2 = t >> 2, p2 = t & 3;
        int4 val = *(const int4*)&ht[h2][p2 * 4];
        const int gb = blk >> 9;                       // batch
        const int s0 = (blk * 16) & (S - 1);           // 16 s-values per block
        *(int4*)&hdst[(gb * H + h2) * S + s0 + p2 * 4] = val;
    }
}

// ---------------------------------------------------------------------------
// Kernel 2: stable counting sort (argsort) of hashes per (b,h).  (unchanged)
// ---------------------------------------------------------------------------
#define SORT_NT 64
#define SORT_CH (S / SORT_NT)   // 128

__global__ __launch_bounds__(SORT_NT) void k_sort(const int* __restrict__ hq,
                                                  const int* __restrict__ hk,
                                                  int* __restrict__ qs,
                                                  int* __restrict__ ks) {
    __shared__ int hist[SORT_NT * 256];
    __shared__ int base[257];
    const int t  = threadIdx.x;
    const int bh = blockIdx.x & (BH - 1);
    const bool isQ = blockIdx.x < BH;
    const int* hp = (isQ ? hq : hk) + bh * S;
    int*       sp = (isQ ? qs : ks) + bh * S;

    for (int i = 0; i < 256; ++i) hist[t * 256 + i] = 0;
    __syncthreads();
    for (int i = 0; i < SORT_CH; ++i) hist[t * 256 + hp[t * SORT_CH + i]]++;
    __syncthreads();

    for (int bi = 0; bi < 4; ++bi) {
        const int bin = t * 4 + bi;
        int sum = 0;
        for (int tt = 0; tt < SORT_NT; ++tt) sum += hist[tt * 256 + bin];
        base[bin + 1] = sum;
    }
    __syncthreads();
    if (t == 0) {
        base[0] = 0;
        for (int i = 1; i <= 256; ++i) base[i] += base[i - 1];
    }
    __syncthreads();

    for (int bi = 0; bi < 4; ++bi) {
        const int bin = t * 4 + bi;
        int run = base[bin];
        for (int tt = 0; tt < SORT_NT; ++tt) {
            int c = hist[tt * 256 + bin];
            hist[tt * 256 + bin] = run;
            run += c;
        }
    }
    __syncthreads();

    for (int i = 0; i < SORT_CH; ++i) {
        const int s0  = t * SORT_CH + i;
        const int bin = hp[s0];
        sp[hist[t * 256 + bin]++] = s0;
    }
}

// ---------------------------------------------------------------------------
// Kernel 3: FUSED attention (R9, proven 146 us / VGPR 112 / no spill).
// (512,2): VGPR budget 128; LDS 54.3 KB caps residency at 2 blocks/CU.
// Q from f32 (inline cvt); K from prep bf16 (compact gathers); V staged
// from f32 with issue-early loads, packed to bf16 in registers pre-barrier.
// One online softmax over 512 keys; swapped QK^T; defer-max; XCD swizzle.
// ---------------------------------------------------------------------------
#define VP 264    // vT pitch (256 + 8 pad)
#define PP 40     // per-wave P pitch (32 + 8 pad)

__global__ __launch_bounds__(512, 2) void k_attn(const float* __restrict__ q,
                                                 const unsigned short* __restrict__ kbf,
                                                 const float* __restrict__ v,
                                                 const int* __restrict__ qs,
                                                 const int* __restrict__ ks,
                                                 const int* __restrict__ sidx,
                                                 float* __restrict__ out) {
    __shared__ __align__(16) unsigned short vT[64 * VP];
    __shared__ __align__(16) unsigned short pL[8 * 32 * PP];

    const int t    = threadIdx.x;
    const int w    = t >> 6;
    const int lane = t & 63;
    const int lg   = lane >> 4;      // 0..3
    const int lr   = lane & 15;      // 0..15
    // XCD swizzle: all 32 blocks of one (b,h) land on one XCD
    const int logical = (blockIdx.x & 7) * (BH * NB / 8) + (blockIdx.x >> 3);
    const int blk  = logical & (NB - 1);
    const int bh   = logical >> 5;
    const int h    = bh & (H - 1), b = bh >> 4;
    const int sbase = bh * S + blk * BS;
    unsigned short* pw = pL + w * 32 * PP;

    // ---- Q B-fragments from f32 (scale 1/8 folded into cvt) ----
    int qrow[2]; bf16x8 bq[2][2];
#pragma unroll
    for (int qg = 0; qg < 2; ++qg) {
        qrow[qg] = qs[sbase + w * 32 + qg * 16 + lr];
        const float* qp = q + (((b * S + qrow[qg]) * H + h) << 6);
#pragma unroll
        for (int kf = 0; kf < 2; ++kf) {
            float4 x0 = ((const float4*)(qp + kf * 32 + lg * 8))[0];
            float4 x1 = ((const float4*)(qp + kf * 32 + lg * 8))[1];
            union { bf16x8 v8; unsigned int u[4]; } fa;
            fa.u[0] = pack2(x0.x * 0.125f, x0.y * 0.125f);
            fa.u[1] = pack2(x0.z * 0.125f, x0.w * 0.125f);
            fa.u[2] = pack2(x1.x * 0.125f, x1.y * 0.125f);
            fa.u[3] = pack2(x1.z * 0.125f, x1.w * 0.125f);
            bq[qg][kf] = fa.v8;
        }
    }

    float m_run[2] = {-1e30f, -1e30f}, l_run[2] = {0.f, 0.f};
    f32x4 acc[2][4];
#pragma unroll
    for (int qg = 0; qg < 2; ++qg)
#pragma unroll
        for (int dg = 0; dg < 4; ++dg) acc[qg][dg] = (f32x4){0.f, 0.f, 0.f, 0.f};

    for (int pass = 0; pass < 2; ++pass) {
        {   // ---- stage V^T from f32: load+convert EARLY, write after barrier ----
            const int key = t >> 1, d0 = (t & 1) * 32;
            const int krow = pass ? sidx[bh * SAMP + key] : ks[sbase + key];
            const float* vp = v + (((b * S + krow) * H + h) << 6) + d0;
            unsigned int uv[16];
#pragma unroll
            for (int i = 0; i < 8; ++i) {
                float4 y = ((const float4*)vp)[i];
                uv[2 * i]     = pack2(y.x, y.y);
                uv[2 * i + 1] = pack2(y.z, y.w);
            }
            if (pass) __syncthreads();          // all reads of old vT done
#pragma unroll
            for (int j = 0; j < 16; ++j) {
                const int d = d0 + 2 * j;
                vT[(d + 0) * VP + key] = (unsigned short)(uv[j]);
                vT[(d + 1) * VP + key] = (unsigned short)(uv[j] >> 16);
            }
        }
        __syncthreads();

        // ---- hoisted key-row indices for all 4 kt4 tiles (static idx) ----
        int kidx[4][4];
#pragma unroll
        for (int kt4 = 0; kt4 < 4; ++kt4)
#pragma unroll
            for (int kg = 0; kg < 4; ++kg) {
                const int key = kt4 * 64 + kg * 16 + lr;
                kidx[kt4][kg] = pass ? sidx[bh * SAMP + key] : ks[sbase + key];
            }

        const float bias = pass ? LOG32 : 0.f;
#pragma unroll
        for (int kt4 = 0; kt4 < 4; ++kt4) {
            // ---- S^T = K Q^T  (A=K frags, B=Q frags) ----
            f32x4 c[2][4];
#pragma unroll
            for (int kf = 0; kf < 2; ++kf) {
                bf16x8 ak[4];
#pragma unroll
                for (int kg = 0; kg < 4; ++kg)
                    ak[kg] = *(const bf16x8*)(kbf + (((b * S + kidx[kt4][kg]) * H + h) << 6)
                                              + kf * 32 + lg * 8);
                __builtin_amdgcn_s_setprio(1);
#pragma unroll
                for (int qg = 0; qg < 2; ++qg)
#pragma unroll
                    for (int kg = 0; kg < 4; ++kg) {
                        f32x4 cin = kf ? c[qg][kg] : (f32x4){0.f, 0.f, 0.f, 0.f};
                        c[qg][kg] = __builtin_amdgcn_mfma_f32_16x16x32_bf16(ak[kg], bq[qg][kf], cin, 0, 0, 0);
                    }
                __builtin_amdgcn_s_setprio(0);
            }
            // ---- online softmax with defer-max (keys in-lane) ----
#pragma unroll
            for (int qg = 0; qg < 2; ++qg) {
                float tm = -1e30f;
#pragma unroll
                for (int kg = 0; kg < 4; ++kg)
#pragma unroll
                    for (int r = 0; r < 4; ++r) tm = fmaxf(tm, c[qg][kg][r]);
                tm = fmaxf(tm, __shfl_xor(tm, 16));
                tm = fmaxf(tm, __shfl_xor(tm, 32));
                tm += bias;
                if (!__all(tm <= m_run[qg] + 8.f)) {
                    const float mn  = fmaxf(m_run[qg], tm);
                    const float es  = __expf(m_run[qg] - mn);
                    m_run[qg] = mn;
                    l_run[qg] *= es;
#pragma unroll
                    for (int r = 0; r < 4; ++r) {
                        const float er = __shfl(es, lg * 4 + r);
#pragma unroll
                        for (int dg = 0; dg < 4; ++dg) acc[qg][dg][r] *= er;
                    }
                }
                const float mnb = m_run[qg] - bias;
                float rs = 0.f;
#pragma unroll
                for (int kg = 0; kg < 4; ++kg)
#pragma unroll
                    for (int r = 0; r < 4; ++r) {
                        const float p = __expf(c[qg][kg][r] - mnb);
                        c[qg][kg][r] = p;
                        rs += p;
                    }
                rs += __shfl_xor(rs, 16);
                rs += __shfl_xor(rs, 32);
                l_run[qg] += rs;
            }
            // ---- PV in 32-key halves: packed P write, b128 reads ----
#pragma unroll
            for (int hh = 0; hh < 2; ++hh) {
#pragma unroll
                for (int qg = 0; qg < 2; ++qg)
#pragma unroll
                    for (int kg2 = 0; kg2 < 2; ++kg2) {
                        const int kg = hh * 2 + kg2;
                        uint2 u;
                        u.x = pack2(c[qg][kg][0], c[qg][kg][1]);
                        u.y = pack2(c[qg][kg][2], c[qg][kg][3]);
                        *(uint2*)&pw[(qg * 16 + lr) * PP + kg2 * 16 + lg * 4] = u;
                    }
                bf16x8 bv[4];
#pragma unroll
                for (int dg = 0; dg < 4; ++dg)
                    bv[dg] = *(const bf16x8*)&vT[(dg * 16 + lr) * VP + kt4 * 64 + hh * 32 + lg * 8];
                bf16x8 ap[2];
#pragma unroll
                for (int qg = 0; qg < 2; ++qg)
                    ap[qg] = *(const bf16x8*)&pw[(qg * 16 + lr) * PP + lg * 8];
                __builtin_amdgcn_s_setprio(1);
#pragma unroll
                for (int qg = 0; qg < 2; ++qg)
#pragma unroll
                    for (int dg = 0; dg < 4; ++dg)
                        acc[qg][dg] = __builtin_amdgcn_mfma_f32_16x16x32_bf16(ap[qg], bv[dg], acc[qg][dg], 0, 0, 0);
                __builtin_amdgcn_s_setprio(0);
            }
        }
    }

    // ---- epilogue: out = acc / l, scattered to original query order ----
#pragma unroll
    for (int qg = 0; qg < 2; ++qg)
#pragma unroll
        for (int r = 0; r < 4; ++r) {
            const float lq = __shfl(l_run[qg], lg * 4 + r);
            const int   qr = __shfl(qrow[qg], lg * 4 + r);
            const float inv = 1.f / lq;
            const int obase = ((b * S + qr) * H + h) << 6;
#pragma unroll
            for (int dg = 0; dg < 4; ++dg)
                out[obase + dg * 16 + lr] = acc[qg][dg][r] * inv;
        }
}

// ---------------------------------------------------------------------------
extern "C" void kernel_launch(void* const* d_in, const int* in_sizes, int n_in,
                              void* d_out, int out_size, void* d_ws, size_t ws_size,
                              hipStream_t stream) {
    const float* q   = (const float*)d_in[0];
    const float* k   = (const float*)d_in[1];
    const float* v   = (const float*)d_in[2];
    const float* pd  = (const float*)d_in[3];
    const int*  sidx = (const int*)d_in[4];
    float* out = (float*)d_out;

    int* hq = (int*)d_ws;
    int* hk = hq + BHS;
    int* qs = hk + BHS;
    int* ks = qs + BHS;
    unsigned short* kbf = (unsigned short*)(ks + BHS);

    k_hash<<<2048, 256, 0, stream>>>(q, k, pd, hq, hk, kbf);
    k_sort<<<2 * BH, SORT_NT, 0, stream>>>(hq, hk, qs, ks);
    k_attn<<<BH * NB, 512, 0, stream>>>(q, kbf, v, qs, ks, sidx, out);
}

// Round 12
// 193.072 us; speedup vs baseline: 1.5208x; 1.0129x over previous
//
#include <hip/hip_runtime.h>
#include <hip/hip_bf16.h>

#define B 2
#define S 8192
#define H 16
#define D 64
#define NB 32          // S / BS
#define BS 256
#define SAMP 256
#define BH (B*H)
#define BHS (B*H*S)
#define BSHD (B*S*H*D)
#define LOG32 3.4657359027997265f   // log(8192/256)

typedef float f32x4 __attribute__((ext_vector_type(4)));
typedef short bf16x8 __attribute__((ext_vector_type(8)));

// Packed f32->bf16 (RNE), single HW instruction (T12; no builtin on gfx950).
// D.lo = bf16(a), D.hi = bf16(b) -- same bits as the old 12-op manual RNE.
__device__ __forceinline__ unsigned int pack2(float a, float b) {
    unsigned int r;
    asm("v_cvt_pk_bf16_f32 %0, %1, %2" : "=v"(r) : "v"(a), "v"(b));
    return r;
}

// ---------------------------------------------------------------------------
// Kernel 1: LSH hash (Q and K) + bf16 pack of K.  Blocks [0,1024) hash Q;
// [1024,2048) hash+pack K.  Quad-cooperative compute (4 rows/quad, 16x64B
// fully-consumed read chunks; spd x4 at pitch 520, conflict-free).  Stores
// go through LDS: tile[256][34 dwords] then 8 x (256 thr x 16B) contiguous
// store instructions (R10 lesson: partial-sector stores amplify HBM 5.3x).
// ---------------------------------------------------------------------------
#define HP 34   // tile pitch in dwords (136 B / row)

__global__ __launch_bounds__(256, 3) void k_hash(const float* __restrict__ q,
                                                 const float* __restrict__ k,
                                                 const float* __restrict__ pd,
                                                 int* __restrict__ hq,
                                                 int* __restrict__ hk,
                                                 unsigned short* __restrict__ kbf) {
    __shared__ float spd4[4 * 520];          // 8320 B
    __shared__ unsigned int tile[256 * HP];  // 34816 B
    __shared__ int ht[16][16];               // 1024 B
    const int t = threadIdx.x;
    for (int i = t; i < 512; i += 256) {
        const float val = pd[i];
        spd4[i] = val; spd4[520 + i] = val;
        spd4[1040 + i] = val; spd4[1560 + i] = val;
    }
    __syncthreads();

    const bool isK = blockIdx.x >= 1024;
    const int  blk = blockIdx.x & 1023;
    const float* src = isK ? k : q;
    int* hdst = isK ? hk : hq;

    const int lane = t & 63;
    const int c    = lane & 3;                          // dim-quarter owner
    const int rql  = (t >> 6) * 64 + (lane >> 2) * 4;   // local row base of quad
    const int rowq = blk * 256 + rql;
    const float* sp = spd4 + c * 520;

    float d[4][8];
#pragma unroll
    for (int rr = 0; rr < 4; ++rr)
#pragma unroll
        for (int p = 0; p < 8; ++p) d[rr][p] = 0.f;

#pragma unroll
    for (int j = 0; j < 4; ++j) {
        float4 x[4];
#pragma unroll
        for (int rr = 0; rr < 4; ++rr)
            x[rr] = *(const float4*)(src + ((rowq + rr) << 6) + j * 16 + c * 4);

        if (isK) {
#pragma unroll
            for (int rr = 0; rr < 4; ++rr) {
                uint2 u2;
                u2.x = pack2(x[rr].x, x[rr].y);
                u2.y = pack2(x[rr].z, x[rr].w);
                *(uint2*)&tile[(rql + rr) * HP + j * 8 + c * 2] = u2;
            }
        }
#pragma unroll
        for (int u = 0; u < 4; ++u) {
            const int dim = j * 16 + c * 4 + u;
            float4 s0 = *(const float4*)&sp[dim * 8];
            float4 s1 = *(const float4*)&sp[dim * 8 + 4];
#pragma unroll
            for (int rr = 0; rr < 4; ++rr) {
                const float xv = (u == 0) ? x[rr].x : (u == 1) ? x[rr].y
                               : (u == 2) ? x[rr].z : x[rr].w;
                d[rr][0] += xv * s0.x; d[rr][1] += xv * s0.y;
                d[rr][2] += xv * s0.z; d[rr][3] += xv * s0.w;
                d[rr][4] += xv * s1.x; d[rr][5] += xv * s1.y;
                d[rr][6] += xv * s1.z; d[rr][7] += xv * s1.w;
            }
        }
    }
#pragma unroll
    for (int rr = 0; rr < 4; ++rr)
#pragma unroll
        for (int p = 0; p < 8; ++p) {
            d[rr][p] += __shfl_xor(d[rr][p], 1);
            d[rr][p] += __shfl_xor(d[rr][p], 2);
        }
    int bits[4];
#pragma unroll
    for (int rr = 0; rr < 4; ++rr) {
        int bv = 0;
#pragma unroll
        for (int p = 0; p < 8; ++p) bv |= (d[rr][p] > 0.f) ? (1 << p) : 0;
        bits[rr] = bv;
    }
    const int myb = (c == 0) ? bits[0] : (c == 1) ? bits[1]
                  : (c == 2) ? bits[2] : bits[3];
    const int myrl = rql + c;                 // local row this lane emits
    ht[myrl & 15][myrl >> 4] = myb ^ (myb >> 1);
    __syncthreads();

    // ---- store phase ----
    if (isK) {
        uint4* dst = (uint4*)(kbf + blk * 256 * 64);   // block-contiguous 32KB
#pragma unroll
        for (int it = 0; it < 8; ++it) {
            const int g = it * 256 + t;                // 256 x 16B = 4KB / instr
            const unsigned int* sl = &tile[(g >> 3) * HP + (g & 7) * 4];
            uint4 val;
            val.x = sl[0]; val.y = sl[1]; val.z = sl[2]; val.w = sl[3];
            dst[g] = val;
        }
    }
    if (t < 64) {       // 16 h-planes x 4 int4 = 64 coalesced stores
        const int h2 = t >> 2, p2 = t & 3;
        int4 val = *(const int4*)&ht[h2][p2 * 4];
        const int gb = blk >> 9;                       // batch
        const int s0 = (blk * 16) & (S - 1);           // 16 s-values per block
        *(int4*)&hdst[(gb * H + h2) * S + s0 + p2 * 4] = val;
    }
}

// ---------------------------------------------------------------------------
// Kernel 2: stable counting sort (argsort) of hashes per (b,h).  (unchanged)
// ---------------------------------------------------------------------------
#define SORT_NT 64
#define SORT_CH (S / SORT_NT)   // 128

__global__ __launch_bounds__(SORT_NT) void k_sort(const int* __restrict__ hq,
                                                  const int* __restrict__ hk,
                                                  int* __restrict__ qs,
                                                  int* __restrict__ ks) {
    __shared__ int hist[SORT_NT * 256];
    __shared__ int base[257];
    const int t  = threadIdx.x;
    const int bh = blockIdx.x & (BH - 1);
    const bool isQ = blockIdx.x < BH;
    const int* hp = (isQ ? hq : hk) + bh * S;
    int*       sp = (isQ ? qs : ks) + bh * S;

    for (int i = 0; i < 256; ++i) hist[t * 256 + i] = 0;
    __syncthreads();
    for (int i = 0; i < SORT_CH; ++i) hist[t * 256 + hp[t * SORT_CH + i]]++;
    __syncthreads();

    for (int bi = 0; bi < 4; ++bi) {
        const int bin = t * 4 + bi;
        int sum = 0;
        for (int tt = 0; tt < SORT_NT; ++tt) sum += hist[tt * 256 + bin];
        base[bin + 1] = sum;
    }
    __syncthreads();
    if (t == 0) {
        base[0] = 0;
        for (int i = 1; i <= 256; ++i) base[i] += base[i - 1];
    }
    __syncthreads();

    for (int bi = 0; bi < 4; ++bi) {
        const int bin = t * 4 + bi;
        int run = base[bin];
        for (int tt = 0; tt < SORT_NT; ++tt) {
            int c = hist[tt * 256 + bin];
            hist[tt * 256 + bin] = run;
            run += c;
        }
    }
    __syncthreads();

    for (int i = 0; i < SORT_CH; ++i) {
        const int s0  = t * SORT_CH + i;
        const int bin = hp[s0];
        sp[hist[t * 256 + bin]++] = s0;
    }
}

// ---------------------------------------------------------------------------
// Kernel 3: FUSED attention (R9/R11 structure; pack2 -> v_cvt_pk_bf16_f32).
// (512,2): VGPR budget 128; LDS 54.3 KB caps residency at 2 blocks/CU.
// Q from f32 (inline cvt); K from prep bf16 (compact gathers); V staged
// from f32 with issue-early loads, packed to bf16 in registers pre-barrier.
// One online softmax over 512 keys; swapped QK^T; defer-max; XCD swizzle.
// ---------------------------------------------------------------------------
#define VP 264    // vT pitch (256 + 8 pad)
#define PP 40     // per-wave P pitch (32 + 8 pad)

__global__ __launch_bounds__(512, 2) void k_attn(const float* __restrict__ q,
                                                 const unsigned short* __restrict__ kbf,
                                                 const float* __restrict__ v,
                                                 const int* __restrict__ qs,
                                                 const int* __restrict__ ks,
                                                 const int* __restrict__ sidx,
                                                 float* __restrict__ out) {
    __shared__ __align__(16) unsigned short vT[64 * VP];
    __shared__ __align__(16) unsigned short pL[8 * 32 * PP];

    const int t    = threadIdx.x;
    const int w    = t >> 6;
    const int lane = t & 63;
    const int lg   = lane >> 4;      // 0..3
    const int lr   = lane & 15;      // 0..15
    // XCD swizzle: all 32 blocks of one (b,h) land on one XCD
    const int logical = (blockIdx.x & 7) * (BH * NB / 8) + (blockIdx.x >> 3);
    const int blk  = logical & (NB - 1);
    const int bh   = logical >> 5;
    const int h    = bh & (H - 1), b = bh >> 4;
    const int sbase = bh * S + blk * BS;
    unsigned short* pw = pL + w * 32 * PP;

    // ---- Q B-fragments from f32 (scale 1/8 folded into cvt) ----
    int qrow[2]; bf16x8 bq[2][2];
#pragma unroll
    for (int qg = 0; qg < 2; ++qg) {
        qrow[qg] = qs[sbase + w * 32 + qg * 16 + lr];
        const float* qp = q + (((b * S + qrow[qg]) * H + h) << 6);
#pragma unroll
        for (int kf = 0; kf < 2; ++kf) {
            float4 x0 = ((const float4*)(qp + kf * 32 + lg * 8))[0];
            float4 x1 = ((const float4*)(qp + kf * 32 + lg * 8))[1];
            union { bf16x8 v8; unsigned int u[4]; } fa;
            fa.u[0] = pack2(x0.x * 0.125f, x0.y * 0.125f);
            fa.u[1] = pack2(x0.z * 0.125f, x0.w * 0.125f);
            fa.u[2] = pack2(x1.x * 0.125f, x1.y * 0.125f);
            fa.u[3] = pack2(x1.z * 0.125f, x1.w * 0.125f);
            bq[qg][kf] = fa.v8;
        }
    }

    float m_run[2] = {-1e30f, -1e30f}, l_run[2] = {0.f, 0.f};
    f32x4 acc[2][4];
#pragma unroll
    for (int qg = 0; qg < 2; ++qg)
#pragma unroll
        for (int dg = 0; dg < 4; ++dg) acc[qg][dg] = (f32x4){0.f, 0.f, 0.f, 0.f};

    for (int pass = 0; pass < 2; ++pass) {
        {   // ---- stage V^T from f32: load+convert EARLY, write after barrier ----
            const int key = t >> 1, d0 = (t & 1) * 32;
            const int krow = pass ? sidx[bh * SAMP + key] : ks[sbase + key];
            const float* vp = v + (((b * S + krow) * H + h) << 6) + d0;
            unsigned int uv[16];
#pragma unroll
            for (int i = 0; i < 8; ++i) {
                float4 y = ((const float4*)vp)[i];
                uv[2 * i]     = pack2(y.x, y.y);
                uv[2 * i + 1] = pack2(y.z, y.w);
            }
            if (pass) __syncthreads();          // all reads of old vT done
#pragma unroll
            for (int j = 0; j < 16; ++j) {
                const int d = d0 + 2 * j;
                vT[(d + 0) * VP + key] = (unsigned short)(uv[j]);
                vT[(d + 1) * VP + key] = (unsigned short)(uv[j] >> 16);
            }
        }
        __syncthreads();

        // ---- hoisted key-row indices for all 4 kt4 tiles (static idx) ----
        int kidx[4][4];
#pragma unroll
        for (int kt4 = 0; kt4 < 4; ++kt4)
#pragma unroll
            for (int kg = 0; kg < 4; ++kg) {
                const int key = kt4 * 64 + kg * 16 + lr;
                kidx[kt4][kg] = pass ? sidx[bh * SAMP + key] : ks[sbase + key];
            }

        const float bias = pass ? LOG32 : 0.f;
#pragma unroll
        for (int kt4 = 0; kt4 < 4; ++kt4) {
            // ---- S^T = K Q^T  (A=K frags, B=Q frags) ----
            f32x4 c[2][4];
#pragma unroll
            for (int kf = 0; kf < 2; ++kf) {
                bf16x8 ak[4];
#pragma unroll
                for (int kg = 0; kg < 4; ++kg)
                    ak[kg] = *(const bf16x8*)(kbf + (((b * S + kidx[kt4][kg]) * H + h) << 6)
                                              + kf * 32 + lg * 8);
                __builtin_amdgcn_s_setprio(1);
#pragma unroll
                for (int qg = 0; qg < 2; ++qg)
#pragma unroll
                    for (int kg = 0; kg < 4; ++kg) {
                        f32x4 cin = kf ? c[qg][kg] : (f32x4){0.f, 0.f, 0.f, 0.f};
                        c[qg][kg] = __builtin_amdgcn_mfma_f32_16x16x32_bf16(ak[kg], bq[qg][kf], cin, 0, 0, 0);
                    }
                __builtin_amdgcn_s_setprio(0);
            }
            // ---- online softmax with defer-max (keys in-lane) ----
#pragma unroll
            for (int qg = 0; qg < 2; ++qg) {
                float tm = -1e30f;
#pragma unroll
                for (int kg = 0; kg < 4; ++kg)
#pragma unroll
                    for (int r = 0; r < 4; ++r) tm = fmaxf(tm, c[qg][kg][r]);
                tm = fmaxf(tm, __shfl_xor(tm, 16));
                tm = fmaxf(tm, __shfl_xor(tm, 32));
                tm += bias;
                if (!__all(tm <= m_run[qg] + 8.f)) {
                    const float mn  = fmaxf(m_run[qg], tm);
                    const float es  = __expf(m_run[qg] - mn);
                    m_run[qg] = mn;
                    l_run[qg] *= es;
#pragma unroll
                    for (int r = 0; r < 4; ++r) {
                        const float er = __shfl(es, lg * 4 + r);
#pragma unroll
                        for (int dg = 0; dg < 4; ++dg) acc[qg][dg][r] *= er;
                    }
                }
                const float mnb = m_run[qg] - bias;
                float rs = 0.f;
#pragma unroll
                for (int kg = 0; kg < 4; ++kg)
#pragma unroll
                    for (int r = 0; r < 4; ++r) {
                        const float p = __expf(c[qg][kg][r] - mnb);
                        c[qg][kg][r] = p;
                        rs += p;
                    }
                rs += __shfl_xor(rs, 16);
                rs += __shfl_xor(rs, 32);
                l_run[qg] += rs;
            }
            // ---- PV in 32-key halves: packed P write (cvt_pk), b128 reads ----
#pragma unroll
            for (int hh = 0; hh < 2; ++hh) {
#pragma unroll
                for (int qg = 0; qg < 2; ++qg)
#pragma unroll
                    for (int kg2 = 0; kg2 < 2; ++kg2) {
                        const int kg = hh * 2 + kg2;
                        uint2 u;
                        u.x = pack2(c[qg][kg][0], c[qg][kg][1]);
                        u.y = pack2(c[qg][kg][2], c[qg][kg][3]);
                        *(uint2*)&pw[(qg * 16 + lr) * PP + kg2 * 16 + lg * 4] = u;
                    }
                bf16x8 bv[4];
#pragma unroll
                for (int dg = 0; dg < 4; ++dg)
                    bv[dg] = *(const bf16x8*)&vT[(dg * 16 + lr) * VP + kt4 * 64 + hh * 32 + lg * 8];
                bf16x8 ap[2];
#pragma unroll
                for (int qg = 0; qg < 2; ++qg)
                    ap[qg] = *(const bf16x8*)&pw[(qg * 16 + lr) * PP + lg * 8];
                __builtin_amdgcn_s_setprio(1);
#pragma unroll
                for (int qg = 0; qg < 2; ++qg)
#pragma unroll
                    for (int dg = 0; dg < 4; ++dg)
                        acc[qg][dg] = __builtin_amdgcn_mfma_f32_16x16x32_bf16(ap[qg], bv[dg], acc[qg][dg], 0, 0, 0);
                __builtin_amdgcn_s_setprio(0);
            }
        }
    }

    // ---- epilogue: out = acc / l, scattered to original query order ----
#pragma unroll
    for (int qg = 0; qg < 2; ++qg)
#pragma unroll
        for (int r = 0; r < 4; ++r) {
            const float lq = __shfl(l_run[qg], lg * 4 + r);
            const int   qr = __shfl(qrow[qg], lg * 4 + r);
            const float inv = 1.f / lq;
            const int obase = ((b * S + qr) * H + h) << 6;
#pragma unroll
            for (int dg = 0; dg < 4; ++dg)
                out[obase + dg * 16 + lr] = acc[qg][dg][r] * inv;
        }
}

// ---------------------------------------------------------------------------
extern "C" void kernel_launch(void* const* d_in, const int* in_sizes, int n_in,
                              void* d_out, int out_size, void* d_ws, size_t ws_size,
                              hipStream_t stream) {
    const float* q   = (const float*)d_in[0];
    const float* k   = (const float*)d_in[1];
    const float* v   = (const float*)d_in[2];
    const float* pd  = (const float*)d_in[3];
    const int*  sidx = (const int*)d_in[4];
    float* out = (float*)d_out;

    int* hq = (int*)d_ws;
    int* hk = hq + BHS;
    int* qs = hk + BHS;
    int* ks = qs + BHS;
    unsigned short* kbf = (unsigned short*)(ks + BHS);

    k_hash<<<2048, 256, 0, stream>>>(q, k, pd, hq, hk, kbf);
    k_sort<<<2 * BH, SORT_NT, 0, stream>>>(hq, hk, qs, ks);
    k_attn<<<BH * NB, 512, 0, stream>>>(q, kbf, v, qs, ks, sidx, out);
}

// Round 13
// 191.229 us; speedup vs baseline: 1.5355x; 1.0096x over previous
//
#include <hip/hip_runtime.h>
#include <hip/hip_bf16.h>

#define B 2
#define S 8192
#define H 16
#define D 64
#define NB 32          // S / BS
#define BS 256
#define SAMP 256
#define BH (B*H)
#define BHS (B*H*S)
#define BSHD (B*S*H*D)
#define LOG32 3.4657359027997265f   // log(8192/256)

typedef float f32x4 __attribute__((ext_vector_type(4)));
typedef short bf16x8 __attribute__((ext_vector_type(8)));

// Packed f32->bf16 (RNE), single HW instruction.
__device__ __forceinline__ unsigned int pack2(float a, float b) {
    unsigned int r;
    asm("v_cvt_pk_bf16_f32 %0, %1, %2" : "=v"(r) : "v"(a), "v"(b));
    return r;
}

// ---------------------------------------------------------------------------
// Kernel 1: LSH hash (Q and K) + bf16 pack of K.  (unchanged from R12)
// ---------------------------------------------------------------------------
#define HP 34   // tile pitch in dwords (136 B / row)

__global__ __launch_bounds__(256, 3) void k_hash(const float* __restrict__ q,
                                                 const float* __restrict__ k,
                                                 const float* __restrict__ pd,
                                                 int* __restrict__ hq,
                                                 int* __restrict__ hk,
                                                 unsigned short* __restrict__ kbf) {
    __shared__ float spd4[4 * 520];          // 8320 B
    __shared__ unsigned int tile[256 * HP];  // 34816 B
    __shared__ int ht[16][16];               // 1024 B
    const int t = threadIdx.x;
    for (int i = t; i < 512; i += 256) {
        const float val = pd[i];
        spd4[i] = val; spd4[520 + i] = val;
        spd4[1040 + i] = val; spd4[1560 + i] = val;
    }
    __syncthreads();

    const bool isK = blockIdx.x >= 1024;
    const int  blk = blockIdx.x & 1023;
    const float* src = isK ? k : q;
    int* hdst = isK ? hk : hq;

    const int lane = t & 63;
    const int c    = lane & 3;                          // dim-quarter owner
    const int rql  = (t >> 6) * 64 + (lane >> 2) * 4;   // local row base of quad
    const int rowq = blk * 256 + rql;
    const float* sp = spd4 + c * 520;

    float d[4][8];
#pragma unroll
    for (int rr = 0; rr < 4; ++rr)
#pragma unroll
        for (int p = 0; p < 8; ++p) d[rr][p] = 0.f;

#pragma unroll
    for (int j = 0; j < 4; ++j) {
        float4 x[4];
#pragma unroll
        for (int rr = 0; rr < 4; ++rr)
            x[rr] = *(const float4*)(src + ((rowq + rr) << 6) + j * 16 + c * 4);

        if (isK) {
#pragma unroll
            for (int rr = 0; rr < 4; ++rr) {
                uint2 u2;
                u2.x = pack2(x[rr].x, x[rr].y);
                u2.y = pack2(x[rr].z, x[rr].w);
                *(uint2*)&tile[(rql + rr) * HP + j * 8 + c * 2] = u2;
            }
        }
#pragma unroll
        for (int u = 0; u < 4; ++u) {
            const int dim = j * 16 + c * 4 + u;
            float4 s0 = *(const float4*)&sp[dim * 8];
            float4 s1 = *(const float4*)&sp[dim * 8 + 4];
#pragma unroll
            for (int rr = 0; rr < 4; ++rr) {
                const float xv = (u == 0) ? x[rr].x : (u == 1) ? x[rr].y
                               : (u == 2) ? x[rr].z : x[rr].w;
                d[rr][0] += xv * s0.x; d[rr][1] += xv * s0.y;
                d[rr][2] += xv * s0.z; d[rr][3] += xv * s0.w;
                d[rr][4] += xv * s1.x; d[rr][5] += xv * s1.y;
                d[rr][6] += xv * s1.z; d[rr][7] += xv * s1.w;
            }
        }
    }
#pragma unroll
    for (int rr = 0; rr < 4; ++rr)
#pragma unroll
        for (int p = 0; p < 8; ++p) {
            d[rr][p] += __shfl_xor(d[rr][p], 1);
            d[rr][p] += __shfl_xor(d[rr][p], 2);
        }
    int bits[4];
#pragma unroll
    for (int rr = 0; rr < 4; ++rr) {
        int bv = 0;
#pragma unroll
        for (int p = 0; p < 8; ++p) bv |= (d[rr][p] > 0.f) ? (1 << p) : 0;
        bits[rr] = bv;
    }
    const int myb = (c == 0) ? bits[0] : (c == 1) ? bits[1]
                  : (c == 2) ? bits[2] : bits[3];
    const int myrl = rql + c;                 // local row this lane emits
    ht[myrl & 15][myrl >> 4] = myb ^ (myb >> 1);
    __syncthreads();

    // ---- store phase ----
    if (isK) {
        uint4* dst = (uint4*)(kbf + blk * 256 * 64);   // block-contiguous 32KB
#pragma unroll
        for (int it = 0; it < 8; ++it) {
            const int g = it * 256 + t;                // 256 x 16B = 4KB / instr
            const unsigned int* sl = &tile[(g >> 3) * HP + (g & 7) * 4];
            uint4 val;
            val.x = sl[0]; val.y = sl[1]; val.z = sl[2]; val.w = sl[3];
            dst[g] = val;
        }
    }
    if (t < 64) {       // 16 h-planes x 4 int4 = 64 coalesced stores
        const int h2 = t >> 2, p2 = t & 3;
        int4 val = *(const int4*)&ht[h2][p2 * 4];
        const int gb = blk >> 9;                       // batch
        const int s0 = (blk * 16) & (S - 1);           // 16 s-values per block
        *(int4*)&hdst[(gb * H + h2) * S + s0 + p2 * 4] = val;
    }
}

// ---------------------------------------------------------------------------
// Kernel 2: stable counting sort.  NEW: the t==0 serial 256-bin prefix
// (~256 dependent LDS RMWs) replaced by a 4-local + wave shfl_up scan.
// ---------------------------------------------------------------------------
#define SORT_NT 64
#define SORT_CH (S / SORT_NT)   // 128

__global__ __launch_bounds__(SORT_NT) void k_sort(const int* __restrict__ hq,
                                                  const int* __restrict__ hk,
                                                  int* __restrict__ qs,
                                                  int* __restrict__ ks) {
    __shared__ int hist[SORT_NT * 256];
    __shared__ int base[257];
    const int t  = threadIdx.x;
    const int bh = blockIdx.x & (BH - 1);
    const bool isQ = blockIdx.x < BH;
    const int* hp = (isQ ? hq : hk) + bh * S;
    int*       sp = (isQ ? qs : ks) + bh * S;

    for (int i = 0; i < 256; ++i) hist[t * 256 + i] = 0;
    __syncthreads();
    for (int i = 0; i < SORT_CH; ++i) hist[t * 256 + hp[t * SORT_CH + i]]++;
    __syncthreads();

    // per-bin totals (4 bins per thread) -> registers
    int v0 = 0, v1 = 0, v2 = 0, v3 = 0;
    for (int tt = 0; tt < SORT_NT; ++tt) {
        const int* hr = &hist[tt * 256 + t * 4];
        v0 += hr[0]; v1 += hr[1]; v2 += hr[2]; v3 += hr[3];
    }
    // wave-parallel exclusive scan over thread totals
    {
        const int s1 = v0 + v1, s2 = s1 + v2, tot = s2 + v3;
        int inc = tot;
#pragma unroll
        for (int dlt = 1; dlt < 64; dlt <<= 1) {
            const int n = __shfl_up(inc, dlt);
            if (t >= dlt) inc += n;
        }
        const int ex = inc - tot;
        base[4 * t + 1] = ex + v0;
        base[4 * t + 2] = ex + s1;
        base[4 * t + 3] = ex + s2;
        base[4 * t + 4] = ex + tot;
        if (t == 0) base[0] = 0;
    }
    __syncthreads();

    for (int bi = 0; bi < 4; ++bi) {
        const int bin = t * 4 + bi;
        int run = base[bin];
        for (int tt = 0; tt < SORT_NT; ++tt) {
            int c = hist[tt * 256 + bin];
            hist[tt * 256 + bin] = run;
            run += c;
        }
    }
    __syncthreads();

    for (int i = 0; i < SORT_CH; ++i) {
        const int s0  = t * SORT_CH + i;
        const int bin = hp[s0];
        sp[hist[t * 256 + bin]++] = s0;
    }
}

// ---------------------------------------------------------------------------
// Kernel 3: FUSED attention.  NEW vs R12:
//  (a) K-prefetch rotated across kt4: next tile's indices + kf0 fragments
//      issued after QK^T, so their ~200-400cy L2 latency hides under
//      softmax+PV (~500cy).  kidx un-hoisted (krw per tile) to pay VGPRs.
//  (b) V-staging remap key=t&255, d0=(t>>8)*32: write banks now
//      (8j + key) over 64 consecutive keys -> conflict-free (was 4-way).
// ---------------------------------------------------------------------------
#define VP 264    // vT pitch (256 + 8 pad)
#define PP 40     // per-wave P pitch (32 + 8 pad)

__global__ __launch_bounds__(512, 2) void k_attn(const float* __restrict__ q,
                                                 const unsigned short* __restrict__ kbf,
                                                 const float* __restrict__ v,
                                                 const int* __restrict__ qs,
                                                 const int* __restrict__ ks,
                                                 const int* __restrict__ sidx,
                                                 float* __restrict__ out) {
    __shared__ __align__(16) unsigned short vT[64 * VP];
    __shared__ __align__(16) unsigned short pL[8 * 32 * PP];

    const int t    = threadIdx.x;
    const int w    = t >> 6;
    const int lane = t & 63;
    const int lg   = lane >> 4;      // 0..3
    const int lr   = lane & 15;      // 0..15
    // XCD swizzle: all 32 blocks of one (b,h) land on one XCD
    const int logical = (blockIdx.x & 7) * (BH * NB / 8) + (blockIdx.x >> 3);
    const int blk  = logical & (NB - 1);
    const int bh   = logical >> 5;
    const int h    = bh & (H - 1), b = bh >> 4;
    const int sbase = bh * S + blk * BS;
    unsigned short* pw = pL + w * 32 * PP;

    // ---- Q B-fragments from f32 (scale 1/8 folded into cvt) ----
    int qrow[2]; bf16x8 bq[2][2];
#pragma unroll
    for (int qg = 0; qg < 2; ++qg) {
        qrow[qg] = qs[sbase + w * 32 + qg * 16 + lr];
        const float* qp = q + (((b * S + qrow[qg]) * H + h) << 6);
#pragma unroll
        for (int kf = 0; kf < 2; ++kf) {
            float4 x0 = ((const float4*)(qp + kf * 32 + lg * 8))[0];
            float4 x1 = ((const float4*)(qp + kf * 32 + lg * 8))[1];
            union { bf16x8 v8; unsigned int u[4]; } fa;
            fa.u[0] = pack2(x0.x * 0.125f, x0.y * 0.125f);
            fa.u[1] = pack2(x0.z * 0.125f, x0.w * 0.125f);
            fa.u[2] = pack2(x1.x * 0.125f, x1.y * 0.125f);
            fa.u[3] = pack2(x1.z * 0.125f, x1.w * 0.125f);
            bq[qg][kf] = fa.v8;
        }
    }

    float m_run[2] = {-1e30f, -1e30f}, l_run[2] = {0.f, 0.f};
    f32x4 acc[2][4];
#pragma unroll
    for (int qg = 0; qg < 2; ++qg)
#pragma unroll
        for (int dg = 0; dg < 4; ++dg) acc[qg][dg] = (f32x4){0.f, 0.f, 0.f, 0.f};

    for (int pass = 0; pass < 2; ++pass) {
        {   // ---- stage V^T from f32: load+convert EARLY, write after barrier
            //      key=t&255 (64 consecutive keys/wave) -> conflict-free writes
            const int key = t & 255, d0 = (t >> 8) * 32;
            const int krow = pass ? sidx[bh * SAMP + key] : ks[sbase + key];
            const float* vp = v + (((b * S + krow) * H + h) << 6) + d0;
            unsigned int uv[16];
#pragma unroll
            for (int i = 0; i < 8; ++i) {
                float4 y = ((const float4*)vp)[i];
                uv[2 * i]     = pack2(y.x, y.y);
                uv[2 * i + 1] = pack2(y.z, y.w);
            }
            if (pass) __syncthreads();          // all reads of old vT done
#pragma unroll
            for (int j = 0; j < 16; ++j) {
                const int d = d0 + 2 * j;
                vT[(d + 0) * VP + key] = (unsigned short)(uv[j]);
                vT[(d + 1) * VP + key] = (unsigned short)(uv[j] >> 16);
            }
        }
        __syncthreads();

        const float bias = pass ? LOG32 : 0.f;

        // ---- prefetch tile 0: key indices + kf0 K-fragments ----
        int krw[4]; bf16x8 akp[4];
#pragma unroll
        for (int kg = 0; kg < 4; ++kg) {
            const int key = kg * 16 + lr;
            krw[kg] = pass ? sidx[bh * SAMP + key] : ks[sbase + key];
        }
#pragma unroll
        for (int kg = 0; kg < 4; ++kg)
            akp[kg] = *(const bf16x8*)(kbf + (((b * S + krw[kg]) * H + h) << 6) + lg * 8);

#pragma unroll
        for (int kt4 = 0; kt4 < 4; ++kt4) {
            // kf=1 fragments for the current tile
            bf16x8 ak1[4];
#pragma unroll
            for (int kg = 0; kg < 4; ++kg)
                ak1[kg] = *(const bf16x8*)(kbf + (((b * S + krw[kg]) * H + h) << 6)
                                           + 32 + lg * 8);
            // ---- S^T = K Q^T ----
            f32x4 c[2][4];
            __builtin_amdgcn_s_setprio(1);
#pragma unroll
            for (int qg = 0; qg < 2; ++qg)
#pragma unroll
                for (int kg = 0; kg < 4; ++kg) {
                    f32x4 z = (f32x4){0.f, 0.f, 0.f, 0.f};
                    z = __builtin_amdgcn_mfma_f32_16x16x32_bf16(akp[kg], bq[qg][0], z, 0, 0, 0);
                    c[qg][kg] = __builtin_amdgcn_mfma_f32_16x16x32_bf16(ak1[kg], bq[qg][1], z, 0, 0, 0);
                }
            __builtin_amdgcn_s_setprio(0);

            // ---- prefetch NEXT tile (indices then kf0 frags): latency hides
            //      under softmax + PV below ----
            int krwn[4]; bf16x8 akn[4];
            if (kt4 < 3) {
#pragma unroll
                for (int kg = 0; kg < 4; ++kg) {
                    const int key = (kt4 + 1) * 64 + kg * 16 + lr;
                    krwn[kg] = pass ? sidx[bh * SAMP + key] : ks[sbase + key];
                }
#pragma unroll
                for (int kg = 0; kg < 4; ++kg)
                    akn[kg] = *(const bf16x8*)(kbf + (((b * S + krwn[kg]) * H + h) << 6)
                                               + lg * 8);
            }

            // ---- online softmax with defer-max (keys in-lane) ----
#pragma unroll
            for (int qg = 0; qg < 2; ++qg) {
                float tm = -1e30f;
#pragma unroll
                for (int kg = 0; kg < 4; ++kg)
#pragma unroll
                    for (int r = 0; r < 4; ++r) tm = fmaxf(tm, c[qg][kg][r]);
                tm = fmaxf(tm, __shfl_xor(tm, 16));
                tm = fmaxf(tm, __shfl_xor(tm, 32));
                tm += bias;
                if (!__all(tm <= m_run[qg] + 8.f)) {
                    const float mn  = fmaxf(m_run[qg], tm);
                    const float es  = __expf(m_run[qg] - mn);
                    m_run[qg] = mn;
                    l_run[qg] *= es;
#pragma unroll
                    for (int r = 0; r < 4; ++r) {
                        const float er = __shfl(es, lg * 4 + r);
#pragma unroll
                        for (int dg = 0; dg < 4; ++dg) acc[qg][dg][r] *= er;
                    }
                }
                const float mnb = m_run[qg] - bias;
                float rs = 0.f;
#pragma unroll
                for (int kg = 0; kg < 4; ++kg)
#pragma unroll
                    for (int r = 0; r < 4; ++r) {
                        const float p = __expf(c[qg][kg][r] - mnb);
                        c[qg][kg][r] = p;
                        rs += p;
                    }
                rs += __shfl_xor(rs, 16);
                rs += __shfl_xor(rs, 32);
                l_run[qg] += rs;
            }
            // ---- PV in 32-key halves: packed P write (cvt_pk), b128 reads ----
#pragma unroll
            for (int hh = 0; hh < 2; ++hh) {
#pragma unroll
                for (int qg = 0; qg < 2; ++qg)
#pragma unroll
                    for (int kg2 = 0; kg2 < 2; ++kg2) {
                        const int kg = hh * 2 + kg2;
                        uint2 u;
                        u.x = pack2(c[qg][kg][0], c[qg][kg][1]);
                        u.y = pack2(c[qg][kg][2], c[qg][kg][3]);
                        *(uint2*)&pw[(qg * 16 + lr) * PP + kg2 * 16 + lg * 4] = u;
                    }
                bf16x8 bv[4];
#pragma unroll
                for (int dg = 0; dg < 4; ++dg)
                    bv[dg] = *(const bf16x8*)&vT[(dg * 16 + lr) * VP + kt4 * 64 + hh * 32 + lg * 8];
                bf16x8 ap[2];
#pragma unroll
                for (int qg = 0; qg < 2; ++qg)
                    ap[qg] = *(const bf16x8*)&pw[(qg * 16 + lr) * PP + lg * 8];
                __builtin_amdgcn_s_setprio(1);
#pragma unroll
                for (int qg = 0; qg < 2; ++qg)
#pragma unroll
                    for (int dg = 0; dg < 4; ++dg)
                        acc[qg][dg] = __builtin_amdgcn_mfma_f32_16x16x32_bf16(ap[qg], bv[dg], acc[qg][dg], 0, 0, 0);
                __builtin_amdgcn_s_setprio(0);
            }

            // rotate prefetched tile into place (register renaming, no copies)
            if (kt4 < 3) {
#pragma unroll
                for (int kg = 0; kg < 4; ++kg) { krw[kg] = krwn[kg]; akp[kg] = akn[kg]; }
            }
        }
    }

    // ---- epilogue: out = acc / l, scattered to original query order ----
#pragma unroll
    for (int qg = 0; qg < 2; ++qg)
#pragma unroll
        for (int r = 0; r < 4; ++r) {
            const float lq = __shfl(l_run[qg], lg * 4 + r);
            const int   qr = __shfl(qrow[qg], lg * 4 + r);
            const float inv = 1.f / lq;
            const int obase = ((b * S + qr) * H + h) << 6;
#pragma unroll
            for (int dg = 0; dg < 4; ++dg)
                out[obase + dg * 16 + lr] = acc[qg][dg][r] * inv;
        }
}

// ---------------------------------------------------------------------------
extern "C" void kernel_launch(void* const* d_in, const int* in_sizes, int n_in,
                              void* d_out, int out_size, void* d_ws, size_t ws_size,
                              hipStream_t stream) {
    const float* q   = (const float*)d_in[0];
    const float* k   = (const float*)d_in[1];
    const float* v   = (const float*)d_in[2];
    const float* pd  = (const float*)d_in[3];
    const int*  sidx = (const int*)d_in[4];
    float* out = (float*)d_out;

    int* hq = (int*)d_ws;
    int* hk = hq + BHS;
    int* qs = hk + BHS;
    int* ks = qs + BHS;
    unsigned short* kbf = (unsigned short*)(ks + BHS);

    k_hash<<<2048, 256, 0, stream>>>(q, k, pd, hq, hk, kbf);
    k_sort<<<2 * BH, SORT_NT, 0, stream>>>(hq, hk, qs, ks);
    k_attn<<<BH * NB, 512, 0, stream>>>(q, kbf, v, qs, ks, sidx, out);
}

// Round 14
// 188.623 us; speedup vs baseline: 1.5567x; 1.0138x over previous
//
#include <hip/hip_runtime.h>
#include <hip/hip_bf16.h>

#define B 2
#define S 8192
#define H 16
#define D 64
#define NB 32          // S / BS
#define BS 256
#define SAMP 256
#define BH (B*H)
#define BHS (B*H*S)
#define BSHD (B*S*H*D)
#define LOG32 3.4657359027997265f   // log(8192/256)

typedef float f32x4 __attribute__((ext_vector_type(4)));
typedef short bf16x8 __attribute__((ext_vector_type(8)));

// Packed f32->bf16 (RNE), single HW instruction.
__device__ __forceinline__ unsigned int pack2(float a, float b) {
    unsigned int r;
    asm("v_cvt_pk_bf16_f32 %0, %1, %2" : "=v"(r) : "v"(a), "v"(b));
    return r;
}

// ---------------------------------------------------------------------------
// Kernel 1: LSH hash (Q and K) + bf16 pack of K.  (unchanged from R12/R13 —
// at its 268 MB cold-read floor, ~40 us)
// ---------------------------------------------------------------------------
#define HP 34   // tile pitch in dwords (136 B / row)

__global__ __launch_bounds__(256, 3) void k_hash(const float* __restrict__ q,
                                                 const float* __restrict__ k,
                                                 const float* __restrict__ pd,
                                                 int* __restrict__ hq,
                                                 int* __restrict__ hk,
                                                 unsigned short* __restrict__ kbf) {
    __shared__ float spd4[4 * 520];          // 8320 B
    __shared__ unsigned int tile[256 * HP];  // 34816 B
    __shared__ int ht[16][16];               // 1024 B
    const int t = threadIdx.x;
    for (int i = t; i < 512; i += 256) {
        const float val = pd[i];
        spd4[i] = val; spd4[520 + i] = val;
        spd4[1040 + i] = val; spd4[1560 + i] = val;
    }
    __syncthreads();

    const bool isK = blockIdx.x >= 1024;
    const int  blk = blockIdx.x & 1023;
    const float* src = isK ? k : q;
    int* hdst = isK ? hk : hq;

    const int lane = t & 63;
    const int c    = lane & 3;                          // dim-quarter owner
    const int rql  = (t >> 6) * 64 + (lane >> 2) * 4;   // local row base of quad
    const int rowq = blk * 256 + rql;
    const float* sp = spd4 + c * 520;

    float d[4][8];
#pragma unroll
    for (int rr = 0; rr < 4; ++rr)
#pragma unroll
        for (int p = 0; p < 8; ++p) d[rr][p] = 0.f;

#pragma unroll
    for (int j = 0; j < 4; ++j) {
        float4 x[4];
#pragma unroll
        for (int rr = 0; rr < 4; ++rr)
            x[rr] = *(const float4*)(src + ((rowq + rr) << 6) + j * 16 + c * 4);

        if (isK) {
#pragma unroll
            for (int rr = 0; rr < 4; ++rr) {
                uint2 u2;
                u2.x = pack2(x[rr].x, x[rr].y);
                u2.y = pack2(x[rr].z, x[rr].w);
                *(uint2*)&tile[(rql + rr) * HP + j * 8 + c * 2] = u2;
            }
        }
#pragma unroll
        for (int u = 0; u < 4; ++u) {
            const int dim = j * 16 + c * 4 + u;
            float4 s0 = *(const float4*)&sp[dim * 8];
            float4 s1 = *(const float4*)&sp[dim * 8 + 4];
#pragma unroll
            for (int rr = 0; rr < 4; ++rr) {
                const float xv = (u == 0) ? x[rr].x : (u == 1) ? x[rr].y
                               : (u == 2) ? x[rr].z : x[rr].w;
                d[rr][0] += xv * s0.x; d[rr][1] += xv * s0.y;
                d[rr][2] += xv * s0.z; d[rr][3] += xv * s0.w;
                d[rr][4] += xv * s1.x; d[rr][5] += xv * s1.y;
                d[rr][6] += xv * s1.z; d[rr][7] += xv * s1.w;
            }
        }
    }
#pragma unroll
    for (int rr = 0; rr < 4; ++rr)
#pragma unroll
        for (int p = 0; p < 8; ++p) {
            d[rr][p] += __shfl_xor(d[rr][p], 1);
            d[rr][p] += __shfl_xor(d[rr][p], 2);
        }
    int bits[4];
#pragma unroll
    for (int rr = 0; rr < 4; ++rr) {
        int bv = 0;
#pragma unroll
        for (int p = 0; p < 8; ++p) bv |= (d[rr][p] > 0.f) ? (1 << p) : 0;
        bits[rr] = bv;
    }
    const int myb = (c == 0) ? bits[0] : (c == 1) ? bits[1]
                  : (c == 2) ? bits[2] : bits[3];
    const int myrl = rql + c;                 // local row this lane emits
    ht[myrl & 15][myrl >> 4] = myb ^ (myb >> 1);
    __syncthreads();

    // ---- store phase ----
    if (isK) {
        uint4* dst = (uint4*)(kbf + blk * 256 * 64);   // block-contiguous 32KB
#pragma unroll
        for (int it = 0; it < 8; ++it) {
            const int g = it * 256 + t;                // 256 x 16B = 4KB / instr
            const unsigned int* sl = &tile[(g >> 3) * HP + (g & 7) * 4];
            uint4 val;
            val.x = sl[0]; val.y = sl[1]; val.z = sl[2]; val.w = sl[3];
            dst[g] = val;
        }
    }
    if (t < 64) {       // 16 h-planes x 4 int4 = 64 coalesced stores
        const int h2 = t >> 2, p2 = t & 3;
        int4 val = *(const int4*)&ht[h2][p2 * 4];
        const int gb = blk >> 9;                       // batch
        const int s0 = (blk * 16) & (S - 1);           // 16 s-values per block
        *(int4*)&hdst[(gb * H + h2) * S + s0 + p2 * 4] = val;
    }
}

// ---------------------------------------------------------------------------
// Kernel 2: stable counting sort.  NEW: hist pitch 257 ints -- the per-bin
// loops (stride-256 = single bank, 64-way conflict) now rotate banks.
// ---------------------------------------------------------------------------
#define SORT_NT 64
#define SORT_CH (S / SORT_NT)   // 128
#define HPitch 257

__global__ __launch_bounds__(SORT_NT) void k_sort(const int* __restrict__ hq,
                                                  const int* __restrict__ hk,
                                                  int* __restrict__ qs,
                                                  int* __restrict__ ks) {
    __shared__ int hist[SORT_NT * HPitch];
    __shared__ int base[257];
    const int t  = threadIdx.x;
    const int bh = blockIdx.x & (BH - 1);
    const bool isQ = blockIdx.x < BH;
    const int* hp = (isQ ? hq : hk) + bh * S;
    int*       sp = (isQ ? qs : ks) + bh * S;

    for (int i = 0; i < HPitch; ++i) hist[t * HPitch + i] = 0;
    __syncthreads();
    for (int i = 0; i < SORT_CH; ++i) hist[t * HPitch + hp[t * SORT_CH + i]]++;
    __syncthreads();

    // per-bin totals (4 bins per thread) -> registers
    int v0 = 0, v1 = 0, v2 = 0, v3 = 0;
    for (int tt = 0; tt < SORT_NT; ++tt) {
        const int* hr = &hist[tt * HPitch + t * 4];
        v0 += hr[0]; v1 += hr[1]; v2 += hr[2]; v3 += hr[3];
    }
    // wave-parallel exclusive scan over thread totals
    {
        const int s1 = v0 + v1, s2 = s1 + v2, tot = s2 + v3;
        int inc = tot;
#pragma unroll
        for (int dlt = 1; dlt < 64; dlt <<= 1) {
            const int n = __shfl_up(inc, dlt);
            if (t >= dlt) inc += n;
        }
        const int ex = inc - tot;
        base[4 * t + 1] = ex + v0;
        base[4 * t + 2] = ex + s1;
        base[4 * t + 3] = ex + s2;
        base[4 * t + 4] = ex + tot;
        if (t == 0) base[0] = 0;
    }
    __syncthreads();

    for (int bi = 0; bi < 4; ++bi) {
        const int bin = t * 4 + bi;
        int run = base[bin];
        for (int tt = 0; tt < SORT_NT; ++tt) {
            int c = hist[tt * HPitch + bin];
            hist[tt * HPitch + bin] = run;
            run += c;
        }
    }
    __syncthreads();

    for (int i = 0; i < SORT_CH; ++i) {
        const int s0  = t * SORT_CH + i;
        const int bin = hp[s0];
        sp[hist[t * HPitch + bin]++] = s0;
    }
}

// ---------------------------------------------------------------------------
// Kernel 3: FUSED attention.  NEW vs R13: l (softmax denominator) is
// accumulated as a ONES-COLUMN of V via an extra PV MFMA fragment (acc5) --
// removes the 2 sum-shfls + 16-add chain + l_run bookkeeping per kt4/qg
// (the longest non-hidden serial chain).  Defer-max rescale covers acc5
// automatically.  l self-consistent with acc (both use bf16 P).
// ---------------------------------------------------------------------------
#define VP 264    // vT pitch (256 + 8 pad)
#define PP 40     // per-wave P pitch (32 + 8 pad)

__global__ __launch_bounds__(512, 2) void k_attn(const float* __restrict__ q,
                                                 const unsigned short* __restrict__ kbf,
                                                 const float* __restrict__ v,
                                                 const int* __restrict__ qs,
                                                 const int* __restrict__ ks,
                                                 const int* __restrict__ sidx,
                                                 float* __restrict__ out) {
    __shared__ __align__(16) unsigned short vT[64 * VP];
    __shared__ __align__(16) unsigned short pL[8 * 32 * PP];

    const int t    = threadIdx.x;
    const int w    = t >> 6;
    const int lane = t & 63;
    const int lg   = lane >> 4;      // 0..3
    const int lr   = lane & 15;      // 0..15
    // XCD swizzle: all 32 blocks of one (b,h) land on one XCD
    const int logical = (blockIdx.x & 7) * (BH * NB / 8) + (blockIdx.x >> 3);
    const int blk  = logical & (NB - 1);
    const int bh   = logical >> 5;
    const int h    = bh & (H - 1), b = bh >> 4;
    const int sbase = bh * S + blk * BS;
    unsigned short* pw = pL + w * 32 * PP;

    // ---- Q B-fragments from f32 (scale 1/8 folded into cvt) ----
    int qrow[2]; bf16x8 bq[2][2];
#pragma unroll
    for (int qg = 0; qg < 2; ++qg) {
        qrow[qg] = qs[sbase + w * 32 + qg * 16 + lr];
        const float* qp = q + (((b * S + qrow[qg]) * H + h) << 6);
#pragma unroll
        for (int kf = 0; kf < 2; ++kf) {
            float4 x0 = ((const float4*)(qp + kf * 32 + lg * 8))[0];
            float4 x1 = ((const float4*)(qp + kf * 32 + lg * 8))[1];
            union { bf16x8 v8; unsigned int u[4]; } fa;
            fa.u[0] = pack2(x0.x * 0.125f, x0.y * 0.125f);
            fa.u[1] = pack2(x0.z * 0.125f, x0.w * 0.125f);
            fa.u[2] = pack2(x1.x * 0.125f, x1.y * 0.125f);
            fa.u[3] = pack2(x1.z * 0.125f, x1.w * 0.125f);
            bq[qg][kf] = fa.v8;
        }
    }

    // ones-column B fragment: B[col=0][k]=1, other cols 0 -> lr==0 lanes hold 1.0
    bf16x8 bv5;
    {
        union { bf16x8 v8; unsigned int u[4]; } fo;
        const unsigned int ov = (lr == 0) ? 0x3F803F80u : 0u;
        fo.u[0] = ov; fo.u[1] = ov; fo.u[2] = ov; fo.u[3] = ov;
        bv5 = fo.v8;
    }

    float m_run[2] = {-1e30f, -1e30f};
    f32x4 acc[2][4];
    f32x4 acc5[2];                     // l accumulator (col 0 = sum of P)
#pragma unroll
    for (int qg = 0; qg < 2; ++qg) {
        acc5[qg] = (f32x4){0.f, 0.f, 0.f, 0.f};
#pragma unroll
        for (int dg = 0; dg < 4; ++dg) acc[qg][dg] = (f32x4){0.f, 0.f, 0.f, 0.f};
    }

    for (int pass = 0; pass < 2; ++pass) {
        {   // ---- stage V^T from f32: load+convert EARLY, write after barrier
            const int key = t & 255, d0 = (t >> 8) * 32;
            const int krow = pass ? sidx[bh * SAMP + key] : ks[sbase + key];
            const float* vp = v + (((b * S + krow) * H + h) << 6) + d0;
            unsigned int uv[16];
#pragma unroll
            for (int i = 0; i < 8; ++i) {
                float4 y = ((const float4*)vp)[i];
                uv[2 * i]     = pack2(y.x, y.y);
                uv[2 * i + 1] = pack2(y.z, y.w);
            }
            if (pass) __syncthreads();          // all reads of old vT done
#pragma unroll
            for (int j = 0; j < 16; ++j) {
                const int d = d0 + 2 * j;
                vT[(d + 0) * VP + key] = (unsigned short)(uv[j]);
                vT[(d + 1) * VP + key] = (unsigned short)(uv[j] >> 16);
            }
        }
        __syncthreads();

        const float bias = pass ? LOG32 : 0.f;

        // ---- prefetch tile 0: key indices + kf0 K-fragments ----
        int krw[4]; bf16x8 akp[4];
#pragma unroll
        for (int kg = 0; kg < 4; ++kg) {
            const int key = kg * 16 + lr;
            krw[kg] = pass ? sidx[bh * SAMP + key] : ks[sbase + key];
        }
#pragma unroll
        for (int kg = 0; kg < 4; ++kg)
            akp[kg] = *(const bf16x8*)(kbf + (((b * S + krw[kg]) * H + h) << 6) + lg * 8);

#pragma unroll
        for (int kt4 = 0; kt4 < 4; ++kt4) {
            // kf=1 fragments for the current tile
            bf16x8 ak1[4];
#pragma unroll
            for (int kg = 0; kg < 4; ++kg)
                ak1[kg] = *(const bf16x8*)(kbf + (((b * S + krw[kg]) * H + h) << 6)
                                           + 32 + lg * 8);
            // ---- S^T = K Q^T ----
            f32x4 c[2][4];
            __builtin_amdgcn_s_setprio(1);
#pragma unroll
            for (int qg = 0; qg < 2; ++qg)
#pragma unroll
                for (int kg = 0; kg < 4; ++kg) {
                    f32x4 z = (f32x4){0.f, 0.f, 0.f, 0.f};
                    z = __builtin_amdgcn_mfma_f32_16x16x32_bf16(akp[kg], bq[qg][0], z, 0, 0, 0);
                    c[qg][kg] = __builtin_amdgcn_mfma_f32_16x16x32_bf16(ak1[kg], bq[qg][1], z, 0, 0, 0);
                }
            __builtin_amdgcn_s_setprio(0);

            // ---- prefetch NEXT tile (latency hides under softmax + PV) ----
            int krwn[4]; bf16x8 akn[4];
            if (kt4 < 3) {
#pragma unroll
                for (int kg = 0; kg < 4; ++kg) {
                    const int key = (kt4 + 1) * 64 + kg * 16 + lr;
                    krwn[kg] = pass ? sidx[bh * SAMP + key] : ks[sbase + key];
                }
#pragma unroll
                for (int kg = 0; kg < 4; ++kg)
                    akn[kg] = *(const bf16x8*)(kbf + (((b * S + krwn[kg]) * H + h) << 6)
                                               + lg * 8);
            }

            // ---- online softmax: max + exp only (sum folded into PV) ----
#pragma unroll
            for (int qg = 0; qg < 2; ++qg) {
                float tm = -1e30f;
#pragma unroll
                for (int kg = 0; kg < 4; ++kg)
#pragma unroll
                    for (int r = 0; r < 4; ++r) tm = fmaxf(tm, c[qg][kg][r]);
                tm = fmaxf(tm, __shfl_xor(tm, 16));
                tm = fmaxf(tm, __shfl_xor(tm, 32));
                tm += bias;
                if (!__all(tm <= m_run[qg] + 8.f)) {
                    const float mn  = fmaxf(m_run[qg], tm);
                    const float es  = __expf(m_run[qg] - mn);
                    m_run[qg] = mn;
#pragma unroll
                    for (int r = 0; r < 4; ++r) {
                        const float er = __shfl(es, lg * 4 + r);
#pragma unroll
                        for (int dg = 0; dg < 4; ++dg) acc[qg][dg][r] *= er;
                        acc5[qg][r] *= er;
                    }
                }
                const float mnb = m_run[qg] - bias;
#pragma unroll
                for (int kg = 0; kg < 4; ++kg)
#pragma unroll
                    for (int r = 0; r < 4; ++r)
                        c[qg][kg][r] = __expf(c[qg][kg][r] - mnb);
            }
            // ---- PV in 32-key halves: packed P write (cvt_pk), b128 reads ----
#pragma unroll
            for (int hh = 0; hh < 2; ++hh) {
#pragma unroll
                for (int qg = 0; qg < 2; ++qg)
#pragma unroll
                    for (int kg2 = 0; kg2 < 2; ++kg2) {
                        const int kg = hh * 2 + kg2;
                        uint2 u;
                        u.x = pack2(c[qg][kg][0], c[qg][kg][1]);
                        u.y = pack2(c[qg][kg][2], c[qg][kg][3]);
                        *(uint2*)&pw[(qg * 16 + lr) * PP + kg2 * 16 + lg * 4] = u;
                    }
                bf16x8 bv[4];
#pragma unroll
                for (int dg = 0; dg < 4; ++dg)
                    bv[dg] = *(const bf16x8*)&vT[(dg * 16 + lr) * VP + kt4 * 64 + hh * 32 + lg * 8];
                bf16x8 ap[2];
#pragma unroll
                for (int qg = 0; qg < 2; ++qg)
                    ap[qg] = *(const bf16x8*)&pw[(qg * 16 + lr) * PP + lg * 8];
                __builtin_amdgcn_s_setprio(1);
#pragma unroll
                for (int qg = 0; qg < 2; ++qg) {
#pragma unroll
                    for (int dg = 0; dg < 4; ++dg)
                        acc[qg][dg] = __builtin_amdgcn_mfma_f32_16x16x32_bf16(ap[qg], bv[dg], acc[qg][dg], 0, 0, 0);
                    acc5[qg] = __builtin_amdgcn_mfma_f32_16x16x32_bf16(ap[qg], bv5, acc5[qg], 0, 0, 0);
                }
                __builtin_amdgcn_s_setprio(0);
            }

            // rotate prefetched tile into place
            if (kt4 < 3) {
#pragma unroll
                for (int kg = 0; kg < 4; ++kg) { krw[kg] = krwn[kg]; akp[kg] = akn[kg]; }
            }
        }
    }

    // ---- epilogue: out = acc / l; l = acc5 col 0 (lane lr==0 of lg group) ----
#pragma unroll
    for (int qg = 0; qg < 2; ++qg)
#pragma unroll
        for (int r = 0; r < 4; ++r) {
            const float lq = __shfl(acc5[qg][r], lg * 16);   // lane (lg, lr=0)
            const int   qr = __shfl(qrow[qg], lg * 4 + r);
            const float inv = 1.f / lq;
            const int obase = ((b * S + qr) * H + h) << 6;
#pragma unroll
            for (int dg = 0; dg < 4; ++dg)
                out[obase + dg * 16 + lr] = acc[qg][dg][r] * inv;
        }
}

// ---------------------------------------------------------------------------
extern "C" void kernel_launch(void* const* d_in, const int* in_sizes, int n_in,
                              void* d_out, int out_size, void* d_ws, size_t ws_size,
                              hipStream_t stream) {
    const float* q   = (const float*)d_in[0];
    const float* k   = (const float*)d_in[1];
    const float* v   = (const float*)d_in[2];
    const float* pd  = (const float*)d_in[3];
    const int*  sidx = (const int*)d_in[4];
    float* out = (float*)d_out;

    int* hq = (int*)d_ws;
    int* hk = hq + BHS;
    int* qs = hk + BHS;
    int* ks = qs + BHS;
    unsigned short* kbf = (unsigned short*)(ks + BHS);

    k_hash<<<2048, 256, 0, stream>>>(q, k, pd, hq, hk, kbf);
    k_sort<<<2 * BH, SORT_NT, 0, stream>>>(hq, hk, qs, ks);
    k_attn<<<BH * NB, 512, 0, stream>>>(q, kbf, v, qs, ks, sidx, out);
}